// Round 1
// baseline (447.306 us; speedup 1.0000x reference)
//
#include <hip/hip_runtime.h>

// DBSCAN, N=16384 points in R^3, eps=0.2, minPts=10.
// Pipeline:
//   k_init    : sq[i], deg=0, parent=i, rootmin=N          (1 launch)
//   k_degree  : deg[i] = #{j : d2(i,j) < eps2}  (N^2 tiled)
//   k_core    : core[i] = deg[i] >= 10
//   k_union   : union-find over core-core eps edges (N^2 tiled)
//   k_flatten : comp[i] = find(i)  (component root = min index)
//   k_rootmin : rootmin[i] = min over core neighbors j of comp[j] (N^2 tiled)
//   k_finalize: renumber roots in scan order, write float labels
//
// Numerics replicate the reference EXACTLY in fp32:
//   sq    = (x*x + y*y) + z*z                   (left-to-right, no FMA fusion)
//   dot   = fma(z,z', fma(y,y', x*x'))          (BLAS k-ordered FMA chain)
//   d2    = (sq_i + sq_j) - 2.0f*dot            (2*dot exact)
//   adj   = d2 < 0.04f                          (float(0.04), NOT 0.2f*0.2f)

#define N_PTS   16384
#define BLOCK   256
#define IPT     4
#define ITILE   (BLOCK * IPT)        // 1024 i-points per block column
#define N_ITILE (N_PTS / ITILE)      // 16
#define JTILE   512                  // j-points staged per block
#define N_JTILE (N_PTS / JTILE)      // 32
#define EPS2    0.04f
#define MINPTS  10

__device__ __forceinline__ float dist2(float px, float py, float pz, float sqi, float4 q) {
    // dot in BLAS k-order with FMA accumulate: c = x*x'; c = fma(y,y',c); c = fma(z,z',c)
    float dot = __fmaf_rn(pz, q.z, __fmaf_rn(py, q.y, __fmul_rn(px, q.x)));
    return __fsub_rn(__fadd_rn(sqi, q.w), __fmul_rn(2.0f, dot));
}

// ---- lock-free union-find (device scope; hook larger root under smaller) ----
__device__ __forceinline__ int uf_find(int* parent, int x) {
    int p = __hip_atomic_load(&parent[x], __ATOMIC_RELAXED, __HIP_MEMORY_SCOPE_AGENT);
    while (p != x) {
        int gp = __hip_atomic_load(&parent[p], __ATOMIC_RELAXED, __HIP_MEMORY_SCOPE_AGENT);
        if (gp != p)  // path halving; benign race
            __hip_atomic_store(&parent[x], gp, __ATOMIC_RELAXED, __HIP_MEMORY_SCOPE_AGENT);
        x = p; p = gp;
    }
    return x;
}

__device__ __forceinline__ void uf_union(int* parent, int a, int b) {
    while (true) {
        a = uf_find(parent, a);
        b = uf_find(parent, b);
        if (a == b) return;
        if (a > b) { int t = a; a = b; b = t; }   // a = smaller -> becomes root
        int expected = b;
        if (__hip_atomic_compare_exchange_strong(&parent[b], &expected, a,
                __ATOMIC_RELAXED, __ATOMIC_RELAXED, __HIP_MEMORY_SCOPE_AGENT))
            return;
    }
}

// ---------------------------------------------------------------------------
__global__ void k_init(const float* __restrict__ pts, float* __restrict__ sq,
                       int* __restrict__ deg, int* __restrict__ parent,
                       int* __restrict__ rootmin) {
    int i = blockIdx.x * BLOCK + threadIdx.x;
    float x = pts[3 * i], y = pts[3 * i + 1], z = pts[3 * i + 2];
    // left-to-right sum of rounded squares (matches np.sum(points*points, axis=1))
    sq[i] = __fadd_rn(__fadd_rn(__fmul_rn(x, x), __fmul_rn(y, y)), __fmul_rn(z, z));
    deg[i] = 0;
    parent[i] = i;
    rootmin[i] = N_PTS;
}

__global__ void k_degree(const float* __restrict__ pts, const float* __restrict__ sq,
                         int* __restrict__ deg) {
    __shared__ float4 sj[JTILE];
    const int tid = threadIdx.x;
    const int i0 = blockIdx.x * ITILE;
    const int j0 = blockIdx.y * JTILE;
    for (int idx = tid; idx < JTILE; idx += BLOCK) {
        int j = j0 + idx;
        sj[idx] = make_float4(pts[3 * j], pts[3 * j + 1], pts[3 * j + 2], sq[j]);
    }
    __syncthreads();
    float px[IPT], py[IPT], pz[IPT], sqi[IPT];
    int cnt[IPT];
#pragma unroll
    for (int k = 0; k < IPT; ++k) {
        int i = i0 + k * BLOCK + tid;
        px[k] = pts[3 * i]; py[k] = pts[3 * i + 1]; pz[k] = pts[3 * i + 2];
        sqi[k] = sq[i]; cnt[k] = 0;
    }
#pragma unroll 4
    for (int j = 0; j < JTILE; ++j) {
        float4 q = sj[j];
#pragma unroll
        for (int k = 0; k < IPT; ++k) {
            float d2 = dist2(px[k], py[k], pz[k], sqi[k], q);
            cnt[k] += (d2 < EPS2) ? 1 : 0;
        }
    }
#pragma unroll
    for (int k = 0; k < IPT; ++k)
        atomicAdd(&deg[i0 + k * BLOCK + tid], cnt[k]);
}

__global__ void k_core(const int* __restrict__ deg, int* __restrict__ core) {
    int i = blockIdx.x * BLOCK + threadIdx.x;
    core[i] = (deg[i] >= MINPTS) ? 1 : 0;
}

__global__ void k_union(const float* __restrict__ pts, const float* __restrict__ sq,
                        const int* __restrict__ core, int* __restrict__ parent) {
    __shared__ float4 sj[JTILE];
    const int tid = threadIdx.x;
    const int i0 = blockIdx.x * ITILE;
    const int j0 = blockIdx.y * JTILE;
    for (int idx = tid; idx < JTILE; idx += BLOCK) {
        int j = j0 + idx;
        // non-core j -> w=1e30 makes d2 huge, auto-excluded by the eps test
        float w = core[j] ? sq[j] : 1e30f;
        sj[idx] = make_float4(pts[3 * j], pts[3 * j + 1], pts[3 * j + 2], w);
    }
    __syncthreads();
    float px[IPT], py[IPT], pz[IPT], sqi[IPT];
    int ii[IPT], ci[IPT];
#pragma unroll
    for (int k = 0; k < IPT; ++k) {
        int i = i0 + k * BLOCK + tid;
        ii[k] = i;
        px[k] = pts[3 * i]; py[k] = pts[3 * i + 1]; pz[k] = pts[3 * i + 2];
        sqi[k] = sq[i]; ci[k] = core[i];
    }
    for (int j = 0; j < JTILE; ++j) {
        float4 q = sj[j];
        int jg = j0 + j;
#pragma unroll
        for (int k = 0; k < IPT; ++k) {
            float d2 = dist2(px[k], py[k], pz[k], sqi[k], q);
            // process each core-core edge once (jg < i); self excluded
            if (ci[k] && jg < ii[k] && d2 < EPS2)
                uf_union(parent, ii[k], jg);
        }
    }
}

__global__ void k_flatten(int* __restrict__ parent, int* __restrict__ comp) {
    int i = blockIdx.x * BLOCK + threadIdx.x;
    comp[i] = uf_find(parent, i);
}

__global__ void k_rootmin(const float* __restrict__ pts, const float* __restrict__ sq,
                          const int* __restrict__ core, const int* __restrict__ comp,
                          int* __restrict__ rootmin) {
    __shared__ float4 sj[JTILE];
    __shared__ int sc[JTILE];
    const int tid = threadIdx.x;
    const int i0 = blockIdx.x * ITILE;
    const int j0 = blockIdx.y * JTILE;
    for (int idx = tid; idx < JTILE; idx += BLOCK) {
        int j = j0 + idx;
        float w = core[j] ? sq[j] : 1e30f;
        sj[idx] = make_float4(pts[3 * j], pts[3 * j + 1], pts[3 * j + 2], w);
        sc[idx] = comp[j];
    }
    __syncthreads();
    float px[IPT], py[IPT], pz[IPT], sqi[IPT];
    int m[IPT];
#pragma unroll
    for (int k = 0; k < IPT; ++k) {
        int i = i0 + k * BLOCK + tid;
        px[k] = pts[3 * i]; py[k] = pts[3 * i + 1]; pz[k] = pts[3 * i + 2];
        sqi[k] = sq[i]; m[k] = N_PTS;
    }
#pragma unroll 2
    for (int j = 0; j < JTILE; ++j) {
        float4 q = sj[j];
#pragma unroll
        for (int k = 0; k < IPT; ++k) {
            float d2 = dist2(px[k], py[k], pz[k], sqi[k], q);
            if (d2 < EPS2) m[k] = min(m[k], sc[j]);
        }
    }
#pragma unroll
    for (int k = 0; k < IPT; ++k)
        atomicMin(&rootmin[i0 + k * BLOCK + tid], m[k]);
}

// Single block: renumber component roots in scan order, emit float labels.
__global__ void k_finalize(const int* __restrict__ core, const int* __restrict__ comp,
                           const int* __restrict__ rootmin, int* __restrict__ rank,
                           float* __restrict__ out) {
    __shared__ int partial[1024];
    const int tid = threadIdx.x;
    const int CH = N_PTS / 1024;   // 16
    const int base = tid * CH;
    int flags[N_PTS / 1024];
    int s = 0;
#pragma unroll
    for (int k = 0; k < CH; ++k) {
        int i = base + k;
        flags[k] = (core[i] && comp[i] == i) ? 1 : 0;
        s += flags[k];
    }
    partial[tid] = s;
    __syncthreads();
    if (tid == 0) {
        int acc = 0;
        for (int t = 0; t < 1024; ++t) { int v = partial[t]; partial[t] = acc; acc += v; }
    }
    __syncthreads();
    int acc = partial[tid];
#pragma unroll
    for (int k = 0; k < CH; ++k) {
        acc += flags[k];
        rank[base + k] = acc - 1;   // inclusive cumsum - 1
    }
    __threadfence_block();
    __syncthreads();
#pragma unroll
    for (int k = 0; k < CH; ++k) {
        int i = base + k;
        int rm = rootmin[i];
        out[i] = (rm < N_PTS) ? (float)rank[rm] : -1.0f;
    }
}

extern "C" void kernel_launch(void* const* d_in, const int* in_sizes, int n_in,
                              void* d_out, int out_size, void* d_ws, size_t ws_size,
                              hipStream_t stream) {
    (void)in_sizes; (void)n_in; (void)out_size; (void)ws_size;
    const float* pts = (const float*)d_in[0];
    float* out = (float*)d_out;

    // workspace layout: 6 arrays of N_PTS 4-byte words (384 KB total)
    float* sq      = (float*)d_ws;
    int*   ibase   = (int*)d_ws;
    int*   deg     = ibase + 1 * N_PTS;
    int*   core    = ibase + 2 * N_PTS;
    int*   parent  = ibase + 3 * N_PTS;
    int*   comp    = ibase + 4 * N_PTS;
    int*   rootmin = ibase + 5 * N_PTS;
    int*   rank    = deg;  // deg is dead after k_core; reuse for rank

    dim3 blk(BLOCK);
    dim3 grid1(N_PTS / BLOCK);            // 64
    dim3 gridNN(N_ITILE, N_JTILE);        // 16 x 32

    k_init<<<grid1, blk, 0, stream>>>(pts, sq, deg, parent, rootmin);
    k_degree<<<gridNN, blk, 0, stream>>>(pts, sq, deg);
    k_core<<<grid1, blk, 0, stream>>>(deg, core);
    k_union<<<gridNN, blk, 0, stream>>>(pts, sq, core, parent);
    k_flatten<<<grid1, blk, 0, stream>>>(parent, comp);
    k_rootmin<<<gridNN, blk, 0, stream>>>(pts, sq, core, comp, rootmin);
    k_finalize<<<1, 1024, 0, stream>>>(core, comp, rootmin, rank, out);
}